// Round 2
// baseline (4529.118 us; speedup 1.0000x reference)
//
#include <hip/hip_runtime.h>

#define EPS 1e-5f

// ---------------------------------------------------------------------------
// conv_bn for z: [32,256,8,8] -> [32,256,6,6]
// one output row (6 elems) per thread; 49152 threads per path launch
// ---------------------------------------------------------------------------
__global__ __launch_bounds__(256) void conv_z_kernel(
    const float* __restrict__ z, const float* __restrict__ w,
    const float* __restrict__ gg, const float* __restrict__ bb,
    const float* __restrict__ mm, const float* __restrict__ vv,
    float* __restrict__ out)
{
  int t = blockIdx.x * 256 + threadIdx.x;      // < 32*256*6 = 49152
  int oh = t % 6;
  int co = (t / 6) & 255;
  int b  = t / (6 * 256);
  const float* zb = z + (size_t)b * 256 * 64;
  const float* wc = w + (size_t)co * 2304;
  float acc[6] = {0.f, 0.f, 0.f, 0.f, 0.f, 0.f};
  for (int ci = 0; ci < 256; ++ci) {
    const float* p = zb + ci * 64 + oh * 8;
    float xv[3][8];
#pragma unroll
    for (int r = 0; r < 3; ++r) {
      float4 a = *reinterpret_cast<const float4*>(p + r * 8);
      float4 c = *reinterpret_cast<const float4*>(p + r * 8 + 4);
      xv[r][0] = a.x; xv[r][1] = a.y; xv[r][2] = a.z; xv[r][3] = a.w;
      xv[r][4] = c.x; xv[r][5] = c.y; xv[r][6] = c.z; xv[r][7] = c.w;
    }
    const float* wp = wc + ci * 9;
#pragma unroll
    for (int kh = 0; kh < 3; ++kh)
#pragma unroll
      for (int kw = 0; kw < 3; ++kw) {
        float wv = wp[kh * 3 + kw];
#pragma unroll
        for (int ow = 0; ow < 6; ++ow)
          acc[ow] += xv[kh][ow + kw] * wv;
      }
  }
  float inv  = gg[co] * rsqrtf(vv[co] + EPS);
  float beta = bb[co] - mm[co] * inv;
  float* op = out + ((size_t)(b * 256 + co) * 6 + oh) * 6;
#pragma unroll
  for (int ow = 0; ow < 6; ++ow) op[ow] = acc[ow] * inv + beta;
}

// ---------------------------------------------------------------------------
// conv_bn for x: [32,256,32,32] -> [32,256,30,30]
// one wave per (b,co): 8x8 lanes, each computes a 4x4 output micro-tile.
// Coverage is 32x32; stores guarded to 30x30. Clamped boundary loads only
// feed accumulators whose outputs are >=30 (never stored).
// grid 2048 blocks x 256 threads (4 waves = 4 (b,co) pairs per block)
// ---------------------------------------------------------------------------
__global__ __launch_bounds__(256) void conv_x_kernel(
    const float* __restrict__ x, const float* __restrict__ w,
    const float* __restrict__ gg, const float* __restrict__ bb,
    const float* __restrict__ mm, const float* __restrict__ vv,
    float* __restrict__ out)
{
  int idx  = blockIdx.x * 4 + (threadIdx.x >> 6);  // (b,co), 0..8191
  int lane = threadIdx.x & 63;
  int co = idx & 255;
  int b  = idx >> 8;
  int ty = lane >> 3, tx = lane & 7;
  int oh0 = ty * 4, ow0 = tx * 4;
  const float* xb = x + (size_t)b * 256 * 1024;
  const float* wc = w + (size_t)co * 2304;

  int ihc0 = min(oh0 + 0, 31), ihc1 = min(oh0 + 1, 31), ihc2 = min(oh0 + 2, 31);
  int ihc3 = min(oh0 + 3, 31), ihc4 = min(oh0 + 4, 31), ihc5 = min(oh0 + 5, 31);
  int ihc[6] = {ihc0, ihc1, ihc2, ihc3, ihc4, ihc5};
  int iw4 = min(ow0 + 4, 31), iw5 = min(ow0 + 5, 31);

  float acc[4][4] = {};
  for (int ci = 0; ci < 256; ++ci) {
    const float* p = xb + ci * 1024;
    float xv[6][6];
#pragma unroll
    for (int r = 0; r < 6; ++r) {
      const float* pr = p + ihc[r] * 32;
      float4 v = *reinterpret_cast<const float4*>(pr + ow0);  // 16B aligned (ow0 % 4 == 0)
      xv[r][0] = v.x; xv[r][1] = v.y; xv[r][2] = v.z; xv[r][3] = v.w;
      xv[r][4] = pr[iw4]; xv[r][5] = pr[iw5];
    }
    const float* wp = wc + ci * 9;
#pragma unroll
    for (int kh = 0; kh < 3; ++kh)
#pragma unroll
      for (int kw = 0; kw < 3; ++kw) {
        float wv = wp[kh * 3 + kw];
#pragma unroll
        for (int i = 0; i < 4; ++i)
#pragma unroll
          for (int j = 0; j < 4; ++j)
            acc[i][j] += xv[i + kh][j + kw] * wv;
      }
  }
  float inv  = gg[co] * rsqrtf(vv[co] + EPS);
  float beta = bb[co] - mm[co] * inv;
#pragma unroll
  for (int i = 0; i < 4; ++i)
#pragma unroll
    for (int j = 0; j < 4; ++j) {
      int oh = oh0 + i, ow = ow0 + j;
      if (oh < 30 && ow < 30)
        out[(size_t)idx * 900 + oh * 30 + ow] = acc[i][j] * inv + beta;
    }
}

// ---------------------------------------------------------------------------
// depthwise xcorr: per (b,c): [30,30] (x) corr [6,6] (z kernel) -> [25,25]
// block per (b,c); xf+zf staged in LDS.
// ---------------------------------------------------------------------------
__global__ __launch_bounds__(256) void xcorr_kernel(
    const float* __restrict__ zf, const float* __restrict__ xf,
    float* __restrict__ out)
{
  int bc  = blockIdx.x;           // b*256 + c
  int tid = threadIdx.x;
  __shared__ float sz[36];
  __shared__ float sx[900];
  const float* zp = zf + (size_t)bc * 36;
  const float* xp = xf + (size_t)bc * 900;
  for (int i = tid; i < 900; i += 256) sx[i] = xp[i];
  if (tid < 36) sz[tid] = zp[tid];
  __syncthreads();
  for (int pos = tid; pos < 625; pos += 256) {
    int p = pos / 25, q = pos % 25;
    float acc = 0.f;
#pragma unroll
    for (int u = 0; u < 6; ++u)
#pragma unroll
      for (int v = 0; v < 6; ++v)
        acc += sz[u * 6 + v] * sx[(p + u) * 30 + (q + v)];
    out[(size_t)bc * 625 + pos] = acc;
  }
}

// ---------------------------------------------------------------------------
extern "C" void kernel_launch(void* const* d_in, const int* in_sizes, int n_in,
                              void* d_out, int out_size, void* d_ws, size_t ws_size,
                              hipStream_t stream) {
  const float* z = (const float*)d_in[0];
  const float* x = (const float*)d_in[1];
  // param order: cls_z, cls_x, reg_z, reg_x ; each (w,g,b,m,v)
  const float *W[4], *G[4], *Bb[4], *M[4], *V[4];
  for (int p = 0; p < 4; ++p) {
    W[p]  = (const float*)d_in[2 + p * 5 + 0];
    G[p]  = (const float*)d_in[2 + p * 5 + 1];
    Bb[p] = (const float*)d_in[2 + p * 5 + 2];
    M[p]  = (const float*)d_in[2 + p * 5 + 3];
    V[p]  = (const float*)d_in[2 + p * 5 + 4];
  }

  float* ws      = (float*)d_ws;
  float* cls_zf  = ws;                     // 32*256*36   = 294912
  float* reg_zf  = cls_zf + 294912;
  float* cls_xf  = reg_zf + 294912;        // 32*256*900  = 7372800
  float* reg_xf  = cls_xf + 7372800;
  float* outF    = (float*)d_out;          // cls [5120000] then reg [5120000]

  conv_z_kernel<<<192, 256, 0, stream>>>(z, W[0], G[0], Bb[0], M[0], V[0], cls_zf);
  conv_z_kernel<<<192, 256, 0, stream>>>(z, W[2], G[2], Bb[2], M[2], V[2], reg_zf);
  conv_x_kernel<<<2048, 256, 0, stream>>>(x, W[1], G[1], Bb[1], M[1], V[1], cls_xf);
  conv_x_kernel<<<2048, 256, 0, stream>>>(x, W[3], G[3], Bb[3], M[3], V[3], reg_xf);
  xcorr_kernel<<<8192, 256, 0, stream>>>(cls_zf, cls_xf, outF);
  xcorr_kernel<<<8192, 256, 0, stream>>>(reg_zf, reg_xf, outF + 5120000);
}

// Round 4
// 377.967 us; speedup vs baseline: 11.9828x; 11.9828x over previous
//
#include <hip/hip_runtime.h>

#define EPS 1e-5f

typedef __attribute__((ext_vector_type(8))) short bf16x8;
typedef __attribute__((ext_vector_type(4))) float f32x4;
typedef unsigned short ushort_t;

__device__ __forceinline__ ushort_t f2bf(float f) {
  unsigned u = __float_as_uint(f);
  unsigned r = (u + 0x7fffu + ((u >> 16) & 1u)) >> 16;
  return (ushort_t)r;
}
__device__ __forceinline__ float bf2f(ushort_t h) {
  return __uint_as_float((unsigned)h << 16);
}

#define GLDS16(g, l) __builtin_amdgcn_global_load_lds( \
    (const __attribute__((address_space(1))) void*)(g), \
    (__attribute__((address_space(3))) void*)(l), 16, 0, 0)

// ---------------------------------------------------------------------------
// x: [32,256,32,32] f32 NCHW -> [32,32,32,256] bf16 NHWC. block per (b,h).
// ---------------------------------------------------------------------------
__global__ __launch_bounds__(256) void x_nhwc_kernel(
    const float* __restrict__ x, ushort_t* __restrict__ xh)
{
  int b = blockIdx.x >> 5, h = blockIdx.x & 31;
  __shared__ ushort_t t[256][32];
  const float* src = x + (size_t)b * 256 * 1024 + h * 32;
#pragma unroll
  for (int it = 0; it < 32; ++it) {
    int f = it * 256 + threadIdx.x;        // c*32 + w   (8192 = 256*32)
    int c = f >> 5, w = f & 31;
    t[c][w] = f2bf(src[c * 1024 + w]);
  }
  __syncthreads();
  ushort_t* dst = xh + (size_t)(b * 32 + h) * 32 * 256;
#pragma unroll
  for (int it = 0; it < 32; ++it) {
    int f = it * 256 + threadIdx.x;        // w*256 + c
    int w = f >> 8, c = f & 255;
    dst[w * 256 + c] = t[c][w];
  }
}

// z: [32,256,8,8] f32 NCHW -> [32,8,8,256] bf16 NHWC. block per b.
// 256 c x 64 hw = 16384 elements -> 64 iterations of 256 threads.
__global__ __launch_bounds__(256) void z_nhwc_kernel(
    const float* __restrict__ z, ushort_t* __restrict__ zh)
{
  int b = blockIdx.x;
  __shared__ ushort_t t[256][64];
  const float* src = z + (size_t)b * 256 * 64;
#pragma unroll
  for (int it = 0; it < 64; ++it) {
    int f = it * 256 + threadIdx.x;        // c*64 + hw  (16384 = 256*64)
    int c = f >> 6, hw = f & 63;
    t[c][hw] = f2bf(src[c * 64 + hw]);
  }
  __syncthreads();
  ushort_t* dst = zh + (size_t)b * 64 * 256;
#pragma unroll
  for (int it = 0; it < 64; ++it) {
    int f = it * 256 + threadIdx.x;        // hw*256 + c
    int hw = f >> 8, c = f & 255;
    dst[hw * 256 + c] = t[c][hw];
  }
}

// ---------------------------------------------------------------------------
// weights: two [256,256,3,3] f32 -> B [512][2304] bf16, k = tap*256 + ci
// ---------------------------------------------------------------------------
__global__ __launch_bounds__(256) void wt_kernel(
    const float* __restrict__ w0, const float* __restrict__ w1,
    ushort_t* __restrict__ Bm)
{
  int n = blockIdx.x, ci = threadIdx.x;
  const float* src = (n < 256 ? w0 : w1) + (size_t)(n & 255) * 2304 + ci * 9;
  ushort_t* dst = Bm + (size_t)n * 2304 + ci;
#pragma unroll
  for (int tap = 0; tap < 9; ++tap)
    dst[tap * 256] = f2bf(src[tap]);
}

// ---------------------------------------------------------------------------
// implicit-GEMM conv + BN epilogue.
// A = im2col(img NHWC bf16): M x K, m=(b,oh,ow), k=tap*256+ci
// B = [512][2304] bf16 (n-major, k-contig)
// C[m][n] -> out[path][(b*256+co)*OWH + oh*OW+ow], path = n>>8
// tile 128x128, BK=64, 4 waves (2x2), mfma 16x16x32 bf16. grid (Mtiles, 4)
// ---------------------------------------------------------------------------
template<int OW, int OWH, int IW, int IMGSTRIDE, typename OutT>
__global__ __launch_bounds__(256) void conv_gemm_kernel(
    const ushort_t* __restrict__ Aimg, const ushort_t* __restrict__ Bw,
    const float* __restrict__ g0, const float* __restrict__ b0,
    const float* __restrict__ m0, const float* __restrict__ v0,
    const float* __restrict__ g1, const float* __restrict__ b1,
    const float* __restrict__ m1, const float* __restrict__ v1,
    OutT* __restrict__ out0, OutT* __restrict__ out1)
{
  __shared__ ushort_t As[128 * 64];
  __shared__ ushort_t Bs[128 * 64];

  const int tid  = threadIdx.x;
  const int lane = tid & 63;
  const int wave = tid >> 6;
  const int wr   = wave >> 1, wc = wave & 1;
  const int mtile = blockIdx.x, ntile = blockIdx.y;

  // staging: flat = i*256+tid -> row = i*32 + (tid>>3), chunk = tid&7
  int abase[4], bbase[4];
#pragma unroll
  for (int i = 0; i < 4; ++i) {
    int row = i * 32 + (tid >> 3);
    int m_g = mtile * 128 + row;
    int b   = m_g / OWH;
    int s   = m_g - b * OWH;
    int oh  = s / OW;
    int ow  = s - oh * OW;
    abase[i] = (b * IMGSTRIDE + oh * IW + ow) * 256 + (tid & 7) * 8;
    int n_g = ntile * 128 + row;
    bbase[i] = n_g * 2304 + (tid & 7) * 8;
  }

  f32x4 acc[4][4];
#pragma unroll
  for (int i = 0; i < 4; ++i)
#pragma unroll
    for (int j = 0; j < 4; ++j)
      acc[i][j] = (f32x4){0.f, 0.f, 0.f, 0.f};

  const int lrow = lane & 15;
  const int lk   = lane >> 4;
  const int rA   = wr * 64;
  const int rB   = wc * 64;

  for (int ks = 0; ks < 36; ++ks) {
    const int k0  = ks * 64;
    const int tap = k0 >> 8;
    const int ci0 = k0 & 255;
    const int kh  = tap / 3;
    const int kw  = tap - kh * 3;
    const int aoff = (kh * IW + kw) * 256 + ci0;
#pragma unroll
    for (int i = 0; i < 4; ++i) {
      GLDS16(Aimg + abase[i] + aoff, &As[(i * 256 + tid) * 8]);
      GLDS16(Bw + bbase[i] + k0,     &Bs[(i * 256 + tid) * 8]);
    }
    __syncthreads();
#pragma unroll
    for (int kc = 0; kc < 2; ++kc) {
      bf16x8 af[4], bfr[4];
#pragma unroll
      for (int mi = 0; mi < 4; ++mi)
        af[mi] = *(const bf16x8*)&As[(rA + mi * 16 + lrow) * 64 + kc * 32 + lk * 8];
#pragma unroll
      for (int ni = 0; ni < 4; ++ni)
        bfr[ni] = *(const bf16x8*)&Bs[(rB + ni * 16 + lrow) * 64 + kc * 32 + lk * 8];
#pragma unroll
      for (int mi = 0; mi < 4; ++mi)
#pragma unroll
        for (int ni = 0; ni < 4; ++ni)
          acc[mi][ni] = __builtin_amdgcn_mfma_f32_16x16x32_bf16(
              af[mi], bfr[ni], acc[mi][ni], 0, 0, 0);
    }
    __syncthreads();
  }

  // epilogue: BN fold + scatter to NCHW
#pragma unroll
  for (int ni = 0; ni < 4; ++ni) {
    int n_g  = ntile * 128 + rB + ni * 16 + lrow;
    int path = n_g >> 8;
    int co   = n_g & 255;
    const float* G  = path ? g1 : g0;
    const float* Bb = path ? b1 : b0;
    const float* Mm = path ? m1 : m0;
    const float* Vv = path ? v1 : v0;
    float iv = G[co] * rsqrtf(Vv[co] + EPS);
    float be = Bb[co] - Mm[co] * iv;
    OutT* outp = path ? out1 : out0;
#pragma unroll
    for (int mi = 0; mi < 4; ++mi)
#pragma unroll
      for (int r = 0; r < 4; ++r) {
        int m_g = mtile * 128 + rA + mi * 16 + lk * 4 + r;
        int b   = m_g / OWH;
        int s   = m_g - b * OWH;
        float v = acc[mi][ni][r] * iv + be;
        if constexpr (sizeof(OutT) == 2)
          outp[(size_t)(b * 256 + co) * OWH + s] = f2bf(v);
        else
          outp[(size_t)(b * 256 + co) * OWH + s] = v;
      }
  }
}

// ---------------------------------------------------------------------------
// depthwise xcorr: per (b,c): [30,30] bf16 x [6,6] f32 -> [25,25] f32
// ---------------------------------------------------------------------------
__global__ __launch_bounds__(256) void xcorr_kernel(
    const float* __restrict__ zf, const ushort_t* __restrict__ xf,
    float* __restrict__ out)
{
  int bc  = blockIdx.x;
  int tid = threadIdx.x;
  __shared__ float sz[36];
  __shared__ float sx[900];
  const float* zp    = zf + (size_t)bc * 36;
  const ushort_t* xp = xf + (size_t)bc * 900;
  for (int i = tid; i < 900; i += 256) sx[i] = bf2f(xp[i]);
  if (tid < 36) sz[tid] = zp[tid];
  __syncthreads();
  for (int pos = tid; pos < 625; pos += 256) {
    int p = pos / 25, q = pos % 25;
    float acc = 0.f;
#pragma unroll
    for (int u = 0; u < 6; ++u)
#pragma unroll
      for (int v = 0; v < 6; ++v)
        acc += sz[u * 6 + v] * sx[(p + u) * 30 + (q + v)];
    out[(size_t)bc * 625 + pos] = acc;
  }
}

// ---------------------------------------------------------------------------
extern "C" void kernel_launch(void* const* d_in, const int* in_sizes, int n_in,
                              void* d_out, int out_size, void* d_ws, size_t ws_size,
                              hipStream_t stream) {
  const float* z = (const float*)d_in[0];
  const float* x = (const float*)d_in[1];
  // param order: cls_z(0), cls_x(1), reg_z(2), reg_x(3); each (w,g,b,m,v)
  const float *W[4], *G[4], *Bb[4], *M[4], *V[4];
  for (int p = 0; p < 4; ++p) {
    W[p]  = (const float*)d_in[2 + p * 5 + 0];
    G[p]  = (const float*)d_in[2 + p * 5 + 1];
    Bb[p] = (const float*)d_in[2 + p * 5 + 2];
    M[p]  = (const float*)d_in[2 + p * 5 + 3];
    V[p]  = (const float*)d_in[2 + p * 5 + 4];
  }

  char* ws = (char*)d_ws;
  ushort_t* xhwc  = (ushort_t*)ws;  ws += (size_t)32*32*32*256 * 2;   // 16.78 MB
  ushort_t* zhwc  = (ushort_t*)ws;  ws += (size_t)32*8*8*256 * 2;     //  1.05 MB
  ushort_t* Bx    = (ushort_t*)ws;  ws += (size_t)512*2304 * 2;       //  2.36 MB
  ushort_t* Bz    = (ushort_t*)ws;  ws += (size_t)512*2304 * 2;       //  2.36 MB
  ushort_t* cls_xf = (ushort_t*)ws; ws += (size_t)32*256*900 * 2;     // 14.75 MB
  ushort_t* reg_xf = (ushort_t*)ws; ws += (size_t)32*256*900 * 2;     // 14.75 MB
  float* cls_zf   = (float*)ws;     ws += (size_t)32*256*36 * 4;      //  1.18 MB
  float* reg_zf   = (float*)ws;     // + 1.18 MB -> total 54.4 MB (< proven 61.3)

  float* outF = (float*)d_out;

  x_nhwc_kernel<<<1024, 256, 0, stream>>>(x, xhwc);
  z_nhwc_kernel<<<32, 256, 0, stream>>>(z, zhwc);
  wt_kernel<<<512, 256, 0, stream>>>(W[1], W[3], Bx);   // cls_x_w, reg_x_w
  wt_kernel<<<512, 256, 0, stream>>>(W[0], W[2], Bz);   // cls_z_w, reg_z_w

  // x conv: OW=30, OWH=900, IW=32, IMGSTRIDE=1024, Mtiles=225, out bf16
  conv_gemm_kernel<30, 900, 32, 1024, ushort_t><<<dim3(225, 4), 256, 0, stream>>>(
      xhwc, Bx, G[1], Bb[1], M[1], V[1], G[3], Bb[3], M[3], V[3], cls_xf, reg_xf);
  // z conv: OW=6, OWH=36, IW=8, IMGSTRIDE=64, Mtiles=9, out f32
  conv_gemm_kernel<6, 36, 8, 64, float><<<dim3(9, 4), 256, 0, stream>>>(
      zhwc, Bz, G[0], Bb[0], M[0], V[0], G[2], Bb[2], M[2], V[2], cls_zf, reg_zf);

  xcorr_kernel<<<8192, 256, 0, stream>>>(cls_zf, cls_xf, outF);
  xcorr_kernel<<<8192, 256, 0, stream>>>(reg_zf, reg_xf, outF + 5120000);
}

// Round 5
// 277.632 us; speedup vs baseline: 16.3134x; 1.3614x over previous
//
#include <hip/hip_runtime.h>

#define EPS 1e-5f

typedef __attribute__((ext_vector_type(8))) short bf16x8;
typedef __attribute__((ext_vector_type(4))) float f32x4;
typedef __attribute__((ext_vector_type(4))) unsigned short u16x4;
typedef unsigned short ushort_t;

__device__ __forceinline__ ushort_t f2bf(float f) {
  unsigned u = __float_as_uint(f);
  unsigned r = (u + 0x7fffu + ((u >> 16) & 1u)) >> 16;
  return (ushort_t)r;
}
__device__ __forceinline__ float bf2f(ushort_t h) {
  return __uint_as_float((unsigned)h << 16);
}

#define GLDS16(g, l) __builtin_amdgcn_global_load_lds( \
    (const __attribute__((address_space(1))) void*)(g), \
    (__attribute__((address_space(3))) void*)(l), 16, 0, 0)

// ---------------------------------------------------------------------------
// pack: fused NCHW->NHWC bf16 transposes (x, z) + weight repacks (Bx, Bz).
// grid 2080: [0,1024) x-transpose, [1024,1056) z-transpose,
//            [1056,1568) Bx repack, [1568,2080) Bz repack.
// transpose LDS rows padded (34 / 66 ushorts) to kill 32-way bank conflicts.
// ---------------------------------------------------------------------------
__global__ __launch_bounds__(256) void pack_kernel(
    const float* __restrict__ x, const float* __restrict__ z,
    const float* __restrict__ wxa, const float* __restrict__ wxb,
    const float* __restrict__ wza, const float* __restrict__ wzb,
    ushort_t* __restrict__ xh, ushort_t* __restrict__ zh,
    ushort_t* __restrict__ Bxo, ushort_t* __restrict__ Bzo)
{
  __shared__ ushort_t t[256 * 66];
  int id = blockIdx.x;
  int tid = threadIdx.x;
  if (id < 1024) {                       // x: [32,256,32,32] -> [b,h][w][c]
    int b = id >> 5, h = id & 31;
    const float* src = x + (size_t)b * 256 * 1024 + h * 32;
#pragma unroll
    for (int it = 0; it < 32; ++it) {
      int f = it * 256 + tid;            // c*32 + w
      int c = f >> 5, w = f & 31;
      t[c * 34 + w] = f2bf(src[c * 1024 + w]);
    }
    __syncthreads();
    ushort_t* dst = xh + (size_t)(b * 32 + h) * 32 * 256;
#pragma unroll
    for (int it = 0; it < 32; ++it) {
      int f = it * 256 + tid;            // w*256 + c
      int w = f >> 8, c = f & 255;
      dst[w * 256 + c] = t[c * 34 + w];
    }
  } else if (id < 1056) {                // z: [32,256,8,8] -> [b][hw][c]
    int b = id - 1024;
    const float* src = z + (size_t)b * 256 * 64;
#pragma unroll
    for (int it = 0; it < 64; ++it) {
      int f = it * 256 + tid;            // c*64 + hw
      int c = f >> 6, hw = f & 63;
      t[c * 66 + hw] = f2bf(src[c * 64 + hw]);
    }
    __syncthreads();
    ushort_t* dst = zh + (size_t)b * 64 * 256;
#pragma unroll
    for (int it = 0; it < 64; ++it) {
      int f = it * 256 + tid;            // hw*256 + c
      int hw = f >> 8, c = f & 255;
      dst[hw * 256 + c] = t[c * 66 + hw];
    }
  } else {                               // weights -> [n][k], k = tap*256+ci
    int wid = id - 1056;                 // 0..1023
    int isZ = wid >> 9;                  // 0: Bx, 1: Bz
    int n   = wid & 511;
    const float* s0 = isZ ? wza : wxa;
    const float* s1 = isZ ? wzb : wxb;
    const float* src = (n < 256 ? s0 : s1) + (size_t)(n & 255) * 2304 + tid * 9;
    ushort_t* dst = (isZ ? Bzo : Bxo) + (size_t)n * 2304 + tid;
#pragma unroll
    for (int tap = 0; tap < 9; ++tap)
      dst[tap * 256] = f2bf(src[tap]);
  }
}

// ---------------------------------------------------------------------------
// implicit-GEMM conv + BN epilogue, XOR-swizzled LDS (T2 via pre-swizzled
// global source, rule #21: linear gload_lds dest + same XOR on read).
// tile 128x128, BK=64, 4 waves (2x2), mfma 16x16x32 bf16.
// ---------------------------------------------------------------------------
template<int OW, int OWH, int IW, int IMG, typename OutT>
__device__ __forceinline__ void conv_body(
    int mtile, int ntile,
    const ushort_t* __restrict__ Aimg, const ushort_t* __restrict__ Bw,
    const float* __restrict__ g0, const float* __restrict__ b0,
    const float* __restrict__ m0, const float* __restrict__ v0,
    const float* __restrict__ g1, const float* __restrict__ b1,
    const float* __restrict__ m1, const float* __restrict__ v1,
    OutT* __restrict__ out0, OutT* __restrict__ out1,
    ushort_t* As, ushort_t* Bs)
{
  const int tid  = threadIdx.x;
  const int lane = tid & 63;
  const int wave = tid >> 6;
  const int wr   = wave >> 1, wc = wave & 1;

  // staging: flat = i*256+tid -> row = i*32 + (tid>>3); source chunk XOR'd
  const int chunk = (tid & 7) ^ ((tid >> 3) & 7);
  int abase[4], bbase[4];
#pragma unroll
  for (int i = 0; i < 4; ++i) {
    int row = i * 32 + (tid >> 3);
    int m_g = mtile * 128 + row;
    int b   = m_g / OWH;
    int s   = m_g - b * OWH;
    int oh  = s / OW;
    int ow  = s - oh * OW;
    abase[i] = (b * IMG + oh * IW + ow) * 256 + chunk * 8;
    int n_g = ntile * 128 + row;
    bbase[i] = n_g * 2304 + chunk * 8;
  }

  f32x4 acc[4][4];
#pragma unroll
  for (int i = 0; i < 4; ++i)
#pragma unroll
    for (int j = 0; j < 4; ++j)
      acc[i][j] = (f32x4){0.f, 0.f, 0.f, 0.f};

  const int lrow = lane & 15;
  const int lk   = lane >> 4;
  const int rA   = wr * 64;
  const int rB   = wc * 64;
  const int sw   = lrow & 7;             // read-side XOR (row&7 == lrow&7)

  for (int ks = 0; ks < 36; ++ks) {
    const int k0  = ks * 64;
    const int tap = k0 >> 8;
    const int ci0 = k0 & 255;
    const int kh  = tap / 3;
    const int kw  = tap - kh * 3;
    const int aoff = (kh * IW + kw) * 256 + ci0;
#pragma unroll
    for (int i = 0; i < 4; ++i) {
      GLDS16(Aimg + abase[i] + aoff, &As[(i * 256 + tid) * 8]);
      GLDS16(Bw + bbase[i] + k0,     &Bs[(i * 256 + tid) * 8]);
    }
    __syncthreads();
#pragma unroll
    for (int kc = 0; kc < 2; ++kc) {
      bf16x8 af[4], bfr[4];
#pragma unroll
      for (int mi = 0; mi < 4; ++mi)
        af[mi] = *(const bf16x8*)&As[(rA + mi * 16 + lrow) * 64 + (((kc << 2) | lk) ^ sw) * 8];
#pragma unroll
      for (int ni = 0; ni < 4; ++ni)
        bfr[ni] = *(const bf16x8*)&Bs[(rB + ni * 16 + lrow) * 64 + (((kc << 2) | lk) ^ sw) * 8];
#pragma unroll
      for (int mi = 0; mi < 4; ++mi)
#pragma unroll
        for (int ni = 0; ni < 4; ++ni)
          acc[mi][ni] = __builtin_amdgcn_mfma_f32_16x16x32_bf16(
              af[mi], bfr[ni], acc[mi][ni], 0, 0, 0);
    }
    __syncthreads();
  }

  // epilogue: BN fold + packed scatter to NCHW (4 consecutive s per store;
  // s%4==0 at r=0 and never crosses a b boundary since OWH%4==0)
#pragma unroll
  for (int ni = 0; ni < 4; ++ni) {
    int n_g  = ntile * 128 + rB + ni * 16 + lrow;
    int path = n_g >> 8;
    int co   = n_g & 255;
    const float* G  = path ? g1 : g0;
    const float* Bb = path ? b1 : b0;
    const float* Mm = path ? m1 : m0;
    const float* Vv = path ? v1 : v0;
    float iv = G[co] * rsqrtf(Vv[co] + EPS);
    float be = Bb[co] - Mm[co] * iv;
    OutT* outp = path ? out1 : out0;
#pragma unroll
    for (int mi = 0; mi < 4; ++mi) {
      int m_g = mtile * 128 + rA + mi * 16 + lk * 4;
      int b   = m_g / OWH;
      int s   = m_g - b * OWH;
      if constexpr (sizeof(OutT) == 2) {
        u16x4 pk;
#pragma unroll
        for (int r = 0; r < 4; ++r) pk[r] = f2bf(acc[mi][ni][r] * iv + be);
        *reinterpret_cast<u16x4*>(&outp[(size_t)(b * 256 + co) * OWH + s]) = pk;
      } else {
        f32x4 pk;
#pragma unroll
        for (int r = 0; r < 4; ++r) pk[r] = acc[mi][ni][r] * iv + be;
        *reinterpret_cast<f32x4*>(&outp[(size_t)(b * 256 + co) * OWH + s]) = pk;
      }
    }
  }
}

__global__ __launch_bounds__(256) void conv_fused_kernel(
    const ushort_t* __restrict__ xh, const ushort_t* __restrict__ zh,
    const ushort_t* __restrict__ Bx, const ushort_t* __restrict__ Bz,
    const float* Gcx, const float* Bcx, const float* Mcx, const float* Vcx,
    const float* Grx, const float* Brx, const float* Mrx, const float* Vrx,
    const float* Gcz, const float* Bcz, const float* Mcz, const float* Vcz,
    const float* Grz, const float* Brz, const float* Mrz, const float* Vrz,
    ushort_t* __restrict__ cls_xf, ushort_t* __restrict__ reg_xf,
    float* __restrict__ cls_zf, float* __restrict__ reg_zf)
{
  __shared__ ushort_t As[128 * 64];
  __shared__ ushort_t Bs[128 * 64];
  int id = blockIdx.x;
  if (id < 900) {
    // mtile-major: 4 consecutive blocks share one A tile (L2/L3 locality)
    conv_body<30, 900, 32, 1024, ushort_t>(id >> 2, id & 3, xh, Bx,
        Gcx, Bcx, Mcx, Vcx, Grx, Brx, Mrx, Vrx, cls_xf, reg_xf, As, Bs);
  } else {
    int j = id - 900;
    conv_body<6, 36, 8, 64, float>(j >> 2, j & 3, zh, Bz,
        Gcz, Bcz, Mcz, Vcz, Grz, Brz, Mrz, Vrz, cls_zf, reg_zf, As, Bs);
  }
}

// ---------------------------------------------------------------------------
// fused depthwise xcorr: grid 16384; path = id>>13, bc = id & 8191.
// per (b,c): [30,30] bf16 x [6,6] f32 -> [25,25] f32
// ---------------------------------------------------------------------------
__global__ __launch_bounds__(256) void xcorr_kernel(
    const float* __restrict__ cls_zf, const float* __restrict__ reg_zf,
    const ushort_t* __restrict__ cls_xf, const ushort_t* __restrict__ reg_xf,
    float* __restrict__ out)
{
  int id   = blockIdx.x;
  int path = id >> 13;
  int bc   = id & 8191;
  int tid  = threadIdx.x;
  __shared__ float sz[36];
  __shared__ float sx[900];
  const float*    zp = (path ? reg_zf : cls_zf) + (size_t)bc * 36;
  const ushort_t* xp = (path ? reg_xf : cls_xf) + (size_t)bc * 900;
  const unsigned* xp32 = reinterpret_cast<const unsigned*>(xp);
  for (int i = tid; i < 450; i += 256) {
    unsigned u = xp32[i];
    sx[2 * i]     = bf2f((ushort_t)(u & 0xffff));
    sx[2 * i + 1] = bf2f((ushort_t)(u >> 16));
  }
  if (tid < 36) sz[tid] = zp[tid];
  __syncthreads();
  float* op = out + (size_t)path * 5120000 + (size_t)bc * 625;
  for (int pos = tid; pos < 625; pos += 256) {
    int p = pos / 25, q = pos % 25;
    float acc = 0.f;
#pragma unroll
    for (int u = 0; u < 6; ++u)
#pragma unroll
      for (int v = 0; v < 6; ++v)
        acc += sz[u * 6 + v] * sx[(p + u) * 30 + (q + v)];
    op[pos] = acc;
  }
}

// ---------------------------------------------------------------------------
extern "C" void kernel_launch(void* const* d_in, const int* in_sizes, int n_in,
                              void* d_out, int out_size, void* d_ws, size_t ws_size,
                              hipStream_t stream) {
  const float* z = (const float*)d_in[0];
  const float* x = (const float*)d_in[1];
  // param order: cls_z(0), cls_x(1), reg_z(2), reg_x(3); each (w,g,b,m,v)
  const float *W[4], *G[4], *Bb[4], *M[4], *V[4];
  for (int p = 0; p < 4; ++p) {
    W[p]  = (const float*)d_in[2 + p * 5 + 0];
    G[p]  = (const float*)d_in[2 + p * 5 + 1];
    Bb[p] = (const float*)d_in[2 + p * 5 + 2];
    M[p]  = (const float*)d_in[2 + p * 5 + 3];
    V[p]  = (const float*)d_in[2 + p * 5 + 4];
  }

  char* ws = (char*)d_ws;
  ushort_t* xhwc   = (ushort_t*)ws; ws += (size_t)32*32*32*256 * 2;   // 16.78 MB
  ushort_t* zhwc   = (ushort_t*)ws; ws += (size_t)32*8*8*256 * 2;     //  1.05 MB
  ushort_t* Bx     = (ushort_t*)ws; ws += (size_t)512*2304 * 2;       //  2.36 MB
  ushort_t* Bz     = (ushort_t*)ws; ws += (size_t)512*2304 * 2;       //  2.36 MB
  ushort_t* cls_xf = (ushort_t*)ws; ws += (size_t)32*256*900 * 2;     // 14.75 MB
  ushort_t* reg_xf = (ushort_t*)ws; ws += (size_t)32*256*900 * 2;     // 14.75 MB
  float* cls_zf    = (float*)ws;    ws += (size_t)32*256*36 * 4;      //  1.18 MB
  float* reg_zf    = (float*)ws;    // + 1.18 MB -> 54.4 MB total

  float* outF = (float*)d_out;

  pack_kernel<<<2080, 256, 0, stream>>>(x, z, W[1], W[3], W[0], W[2],
                                        xhwc, zhwc, Bx, Bz);
  conv_fused_kernel<<<936, 256, 0, stream>>>(
      xhwc, zhwc, Bx, Bz,
      G[1], Bb[1], M[1], V[1], G[3], Bb[3], M[3], V[3],
      G[0], Bb[0], M[0], V[0], G[2], Bb[2], M[2], V[2],
      cls_xf, reg_xf, cls_zf, reg_zf);
  xcorr_kernel<<<16384, 256, 0, stream>>>(cls_zf, reg_zf, cls_xf, reg_xf, outF);
}

// Round 7
// 267.965 us; speedup vs baseline: 16.9019x; 1.0361x over previous
//
#include <hip/hip_runtime.h>

#define EPS 1e-5f

typedef __attribute__((ext_vector_type(8))) short bf16x8;
typedef __attribute__((ext_vector_type(4))) float f32x4;
typedef __attribute__((ext_vector_type(4))) unsigned short u16x4;
typedef unsigned short ushort_t;

__device__ __forceinline__ ushort_t f2bf(float f) {
  unsigned u = __float_as_uint(f);
  unsigned r = (u + 0x7fffu + ((u >> 16) & 1u)) >> 16;
  return (ushort_t)r;
}
__device__ __forceinline__ float bf2f(ushort_t h) {
  return __uint_as_float((unsigned)h << 16);
}

#define GLDS16(g, l) __builtin_amdgcn_global_load_lds( \
    (const __attribute__((address_space(1))) void*)(g), \
    (__attribute__((address_space(3))) void*)(l), 16, 0, 0)

// ---------------------------------------------------------------------------
// pack: fused NCHW->NHWC bf16 transposes (x, z) + weight repacks (Bx, Bz).
// grid 2080: [0,1024) x-transpose, [1024,1056) z-transpose, [1056,2080) wts.
// All global loads are float4 (16B); transpose done in LDS (scatter on write,
// contiguous u16x4 on read); stores 8B coalesced. Pad 260 keeps 8B alignment.
// ---------------------------------------------------------------------------
__global__ __launch_bounds__(256) void pack_kernel(
    const float* __restrict__ x, const float* __restrict__ z,
    const float* __restrict__ wxa, const float* __restrict__ wxb,
    const float* __restrict__ wza, const float* __restrict__ wzb,
    ushort_t* __restrict__ xh, ushort_t* __restrict__ zh,
    ushort_t* __restrict__ Bxo, ushort_t* __restrict__ Bzo)
{
  __shared__ ushort_t t[64 * 260];       // 33.3 KB; aliased as float for wts
  int id = blockIdx.x;
  int tid = threadIdx.x;
  if (id < 1024) {                       // x: [32,256,32,32] -> [b,h][w][c]
    int b = id >> 5, h = id & 31;
    const float* src = x + (size_t)b * 262144 + h * 32;
#pragma unroll
    for (int it = 0; it < 8; ++it) {     // 2048 quads = 8 * 256
      int f = it * 256 + tid;            // quad index: c = f>>3, wq = f&7
      int c = f >> 3, wq = f & 7;        // w0 = 4*wq
      float4 v = *reinterpret_cast<const float4*>(src + c * 1024 + wq * 4);
      t[(4 * wq + 0) * 260 + c] = f2bf(v.x);
      t[(4 * wq + 1) * 260 + c] = f2bf(v.y);
      t[(4 * wq + 2) * 260 + c] = f2bf(v.z);
      t[(4 * wq + 3) * 260 + c] = f2bf(v.w);
    }
    __syncthreads();
    ushort_t* dst = xh + (size_t)(b * 32 + h) * 8192;
#pragma unroll
    for (int it = 0; it < 8; ++it) {
      int Q = it * 256 + tid;            // 2048 quads: w = Q>>6, c0 = 4*(Q&63)
      int w = Q >> 6, c0 = (Q & 63) * 4;
      u16x4 pk = *reinterpret_cast<const u16x4*>(&t[w * 260 + c0]);
      *reinterpret_cast<u16x4*>(&dst[w * 256 + c0]) = pk;
    }
  } else if (id < 1056) {                // z: [32,256,8,8] -> [b][hw][c]
    int b = id - 1024;
    const float* src = z + (size_t)b * 16384;
#pragma unroll
    for (int it = 0; it < 16; ++it) {    // 4096 quads = 16 * 256
      int f = it * 256 + tid;
      int c = f >> 4, hq = f & 15;
      float4 v = *reinterpret_cast<const float4*>(src + c * 64 + hq * 4);
      t[(4 * hq + 0) * 260 + c] = f2bf(v.x);
      t[(4 * hq + 1) * 260 + c] = f2bf(v.y);
      t[(4 * hq + 2) * 260 + c] = f2bf(v.z);
      t[(4 * hq + 3) * 260 + c] = f2bf(v.w);
    }
    __syncthreads();
    ushort_t* dst = zh + (size_t)b * 16384;
#pragma unroll
    for (int it = 0; it < 16; ++it) {
      int Q = it * 256 + tid;
      int hw = Q >> 6, c0 = (Q & 63) * 4;
      u16x4 pk = *reinterpret_cast<const u16x4*>(&t[hw * 260 + c0]);
      *reinterpret_cast<u16x4*>(&dst[hw * 256 + c0]) = pk;
    }
  } else {                               // weights -> [n][k], k = tap*256+ci
    float* tf = reinterpret_cast<float*>(t);
    int wid = id - 1056;                 // 0..1023
    int isZ = wid >> 9;
    int n   = wid & 511;
    const float* s0 = isZ ? wza : wxa;
    const float* s1 = isZ ? wzb : wxb;
    const float* src = (n < 256 ? s0 : s1) + (size_t)(n & 255) * 2304;
#pragma unroll
    for (int it = 0; it < 3; ++it) {     // 576 quads of f32
      int f = it * 256 + tid;
      if (f < 576) {
        float4 v = *reinterpret_cast<const float4*>(src + f * 4);
        *reinterpret_cast<float4*>(&tf[f * 4]) = v;
      }
    }
    __syncthreads();
    ushort_t* dst = (isZ ? Bzo : Bxo) + (size_t)n * 2304;
#pragma unroll
    for (int it = 0; it < 9; ++it) {
      int k = it * 256 + tid;            // tap*256 + ci
      int tap = k >> 8, ci = k & 255;
      dst[k] = f2bf(tf[ci * 9 + tap]);   // stride-9 LDS read: 2-way max, free
    }
  }
}

// ---------------------------------------------------------------------------
// implicit-GEMM conv + BN epilogue, XOR-swizzled LDS (linear gload_lds dest +
// pre-swizzled global source + same XOR on read; rule #21).
// tile 128x128, BK=64, 4 waves (2x2), mfma 16x16x32 bf16.
// ---------------------------------------------------------------------------
template<int OW, int OWH, int IW, int IMG, typename OutT>
__device__ __forceinline__ void conv_body(
    int mtile, int ntile,
    const ushort_t* __restrict__ Aimg, const ushort_t* __restrict__ Bw,
    const float* __restrict__ g0, const float* __restrict__ b0,
    const float* __restrict__ m0, const float* __restrict__ v0,
    const float* __restrict__ g1, const float* __restrict__ b1,
    const float* __restrict__ m1, const float* __restrict__ v1,
    OutT* __restrict__ out0, OutT* __restrict__ out1,
    ushort_t* As, ushort_t* Bs)
{
  const int tid  = threadIdx.x;
  const int lane = tid & 63;
  const int wave = tid >> 6;
  const int wr   = wave >> 1, wc = wave & 1;

  const int chunk = (tid & 7) ^ ((tid >> 3) & 7);
  int abase[4], bbase[4];
#pragma unroll
  for (int i = 0; i < 4; ++i) {
    int row = i * 32 + (tid >> 3);
    int m_g = mtile * 128 + row;
    int b   = m_g / OWH;
    int s   = m_g - b * OWH;
    int oh  = s / OW;
    int ow  = s - oh * OW;
    abase[i] = (b * IMG + oh * IW + ow) * 256 + chunk * 8;
    int n_g = ntile * 128 + row;
    bbase[i] = n_g * 2304 + chunk * 8;
  }

  f32x4 acc[4][4];
#pragma unroll
  for (int i = 0; i < 4; ++i)
#pragma unroll
    for (int j = 0; j < 4; ++j)
      acc[i][j] = (f32x4){0.f, 0.f, 0.f, 0.f};

  const int lrow = lane & 15;
  const int lk   = lane >> 4;
  const int rA   = wr * 64;
  const int rB   = wc * 64;
  const int sw   = lrow & 7;

  for (int ks = 0; ks < 36; ++ks) {
    const int k0  = ks * 64;
    const int tap = k0 >> 8;
    const int ci0 = k0 & 255;
    const int kh  = tap / 3;
    const int kw  = tap - kh * 3;
    const int aoff = (kh * IW + kw) * 256 + ci0;
#pragma unroll
    for (int i = 0; i < 4; ++i) {
      GLDS16(Aimg + abase[i] + aoff, &As[(i * 256 + tid) * 8]);
      GLDS16(Bw + bbase[i] + k0,     &Bs[(i * 256 + tid) * 8]);
    }
    __syncthreads();
#pragma unroll
    for (int kc = 0; kc < 2; ++kc) {
      bf16x8 af[4], bfr[4];
#pragma unroll
      for (int mi = 0; mi < 4; ++mi)
        af[mi] = *(const bf16x8*)&As[(rA + mi * 16 + lrow) * 64 + (((kc << 2) | lk) ^ sw) * 8];
#pragma unroll
      for (int ni = 0; ni < 4; ++ni)
        bfr[ni] = *(const bf16x8*)&Bs[(rB + ni * 16 + lrow) * 64 + (((kc << 2) | lk) ^ sw) * 8];
#pragma unroll
      for (int mi = 0; mi < 4; ++mi)
#pragma unroll
        for (int ni = 0; ni < 4; ++ni)
          acc[mi][ni] = __builtin_amdgcn_mfma_f32_16x16x32_bf16(
              af[mi], bfr[ni], acc[mi][ni], 0, 0, 0);
    }
    __syncthreads();
  }

#pragma unroll
  for (int ni = 0; ni < 4; ++ni) {
    int n_g  = ntile * 128 + rB + ni * 16 + lrow;
    int path = n_g >> 8;
    int co   = n_g & 255;
    const float* G  = path ? g1 : g0;
    const float* Bb = path ? b1 : b0;
    const float* Mm = path ? m1 : m0;
    const float* Vv = path ? v1 : v0;
    float iv = G[co] * rsqrtf(Vv[co] + EPS);
    float be = Bb[co] - Mm[co] * iv;
    OutT* outp = path ? out1 : out0;
#pragma unroll
    for (int mi = 0; mi < 4; ++mi) {
      int m_g = mtile * 128 + rA + mi * 16 + lk * 4;
      int b   = m_g / OWH;
      int s   = m_g - b * OWH;
      if constexpr (sizeof(OutT) == 2) {
        u16x4 pk;
#pragma unroll
        for (int r = 0; r < 4; ++r) pk[r] = f2bf(acc[mi][ni][r] * iv + be);
        *reinterpret_cast<u16x4*>(&outp[(size_t)(b * 256 + co) * OWH + s]) = pk;
      } else {
        f32x4 pk;
#pragma unroll
        for (int r = 0; r < 4; ++r) pk[r] = acc[mi][ni][r] * iv + be;
        *reinterpret_cast<f32x4*>(&outp[(size_t)(b * 256 + co) * OWH + s]) = pk;
      }
    }
  }
}

__global__ __launch_bounds__(256) void conv_fused_kernel(
    const ushort_t* __restrict__ xh, const ushort_t* __restrict__ zh,
    const ushort_t* __restrict__ Bx, const ushort_t* __restrict__ Bz,
    const float* Gcx, const float* Bcx, const float* Mcx, const float* Vcx,
    const float* Grx, const float* Brx, const float* Mrx, const float* Vrx,
    const float* Gcz, const float* Bcz, const float* Mcz, const float* Vcz,
    const float* Grz, const float* Brz, const float* Mrz, const float* Vrz,
    ushort_t* __restrict__ cls_xf, ushort_t* __restrict__ reg_xf,
    float* __restrict__ cls_zf, float* __restrict__ reg_zf)
{
  __shared__ ushort_t As[128 * 64];
  __shared__ ushort_t Bs[128 * 64];
  int bid = blockIdx.x;
  if (bid < 900) {
    // bijective XCD-chunk swizzle (m204): XCD k owns a contiguous mtile range
    // 900 = 4*113 + 4*112
    int xcd = bid & 7, within = bid >> 3;
    int id = (xcd < 4 ? xcd * 113 : 452 + (xcd - 4) * 112) + within;
    conv_body<30, 900, 32, 1024, ushort_t>(id >> 2, id & 3, xh, Bx,
        Gcx, Bcx, Mcx, Vcx, Grx, Brx, Mrx, Vrx, cls_xf, reg_xf, As, Bs);
  } else {
    int j = bid - 900;                   // z-blocks stay round-robin
    conv_body<6, 36, 8, 64, float>(j >> 2, j & 3, zh, Bz,
        Gcz, Bcz, Mcz, Vcz, Grz, Brz, Mrz, Vrz, cls_zf, reg_zf, As, Bs);
  }
}

// ---------------------------------------------------------------------------
// fused depthwise xcorr: grid 16384; path = id>>13, bc = id & 8191.
// per (b,c): [30,30] bf16 x [6,6] f32 -> [25,25] f32
// staging via u16x4 (8B); z hoisted to 36 registers before the pos loop.
// ---------------------------------------------------------------------------
__global__ __launch_bounds__(256) void xcorr_kernel(
    const float* __restrict__ cls_zf, const float* __restrict__ reg_zf,
    const ushort_t* __restrict__ cls_xf, const ushort_t* __restrict__ reg_xf,
    float* __restrict__ out)
{
  int id   = blockIdx.x;
  int path = id >> 13;
  int bc   = id & 8191;
  int tid  = threadIdx.x;
  __shared__ float szs[36];
  __shared__ float sx[900];
  const float*    zp = (path ? reg_zf : cls_zf) + (size_t)bc * 36;
  const ushort_t* xp = (path ? reg_xf : cls_xf) + (size_t)bc * 900;
  if (tid < 225) {                       // 900 = 225 quads, 8B loads
    u16x4 v = *reinterpret_cast<const u16x4*>(xp + tid * 4);
    sx[tid * 4 + 0] = bf2f(v[0]);
    sx[tid * 4 + 1] = bf2f(v[1]);
    sx[tid * 4 + 2] = bf2f(v[2]);
    sx[tid * 4 + 3] = bf2f(v[3]);
  }
  if (tid < 36) szs[tid] = zp[tid];
  __syncthreads();
  float zreg[36];
#pragma unroll
  for (int i = 0; i < 36; ++i) zreg[i] = szs[i];   // broadcast reads, once
  float* op = out + (size_t)path * 5120000 + (size_t)bc * 625;
  for (int pos = tid; pos < 625; pos += 256) {
    int p = pos / 25, q = pos % 25;
    float acc = 0.f;
#pragma unroll
    for (int u = 0; u < 6; ++u)
#pragma unroll
      for (int v = 0; v < 6; ++v)
        acc += zreg[u * 6 + v] * sx[(p + u) * 30 + (q + v)];
    op[pos] = acc;
  }
}

// ---------------------------------------------------------------------------
extern "C" void kernel_launch(void* const* d_in, const int* in_sizes, int n_in,
                              void* d_out, int out_size, void* d_ws, size_t ws_size,
                              hipStream_t stream) {
  const float* z = (const float*)d_in[0];
  const float* x = (const float*)d_in[1];
  // param order: cls_z(0), cls_x(1), reg_z(2), reg_x(3); each (w,g,b,m,v)
  const float *W[4], *G[4], *Bb[4], *M[4], *V[4];
  for (int p = 0; p < 4; ++p) {
    W[p]  = (const float*)d_in[2 + p * 5 + 0];
    G[p]  = (const float*)d_in[2 + p * 5 + 1];
    Bb[p] = (const float*)d_in[2 + p * 5 + 2];
    M[p]  = (const float*)d_in[2 + p * 5 + 3];
    V[p]  = (const float*)d_in[2 + p * 5 + 4];
  }

  char* ws = (char*)d_ws;
  ushort_t* xhwc   = (ushort_t*)ws; ws += (size_t)32*32*32*256 * 2;   // 16.78 MB
  ushort_t* zhwc   = (ushort_t*)ws; ws += (size_t)32*8*8*256 * 2;     //  1.05 MB
  ushort_t* Bx     = (ushort_t*)ws; ws += (size_t)512*2304 * 2;       //  2.36 MB
  ushort_t* Bz     = (ushort_t*)ws; ws += (size_t)512*2304 * 2;       //  2.36 MB
  ushort_t* cls_xf = (ushort_t*)ws; ws += (size_t)32*256*900 * 2;     // 14.75 MB
  ushort_t* reg_xf = (ushort_t*)ws; ws += (size_t)32*256*900 * 2;     // 14.75 MB
  float* cls_zf    = (float*)ws;    ws += (size_t)32*256*36 * 4;      //  1.18 MB
  float* reg_zf    = (float*)ws;    // + 1.18 MB -> 54.4 MB total

  float* outF = (float*)d_out;

  pack_kernel<<<2080, 256, 0, stream>>>(x, z, W[1], W[3], W[0], W[2],
                                        xhwc, zhwc, Bx, Bz);
  conv_fused_kernel<<<936, 256, 0, stream>>>(
      xhwc, zhwc, Bx, Bz,
      G[1], Bb[1], M[1], V[1], G[3], Bb[3], M[3], V[3],
      G[0], Bb[0], M[0], V[0], G[2], Bb[2], M[2], V[2],
      cls_xf, reg_xf, cls_zf, reg_zf);
  xcorr_kernel<<<16384, 256, 0, stream>>>(cls_zf, reg_zf, cls_xf, reg_xf, outF);
}

// Round 8
// 240.086 us; speedup vs baseline: 18.8645x; 1.1161x over previous
//
#include <hip/hip_runtime.h>

#define EPS 1e-5f

typedef __attribute__((ext_vector_type(8))) short bf16x8;
typedef __attribute__((ext_vector_type(4))) float f32x4;
typedef __attribute__((ext_vector_type(4))) unsigned short u16x4;
typedef unsigned short ushort_t;

__device__ __forceinline__ ushort_t f2bf(float f) {
  unsigned u = __float_as_uint(f);
  unsigned r = (u + 0x7fffu + ((u >> 16) & 1u)) >> 16;
  return (ushort_t)r;
}
__device__ __forceinline__ float bf2f(ushort_t h) {
  return __uint_as_float((unsigned)h << 16);
}

#define GLDS16(g, l) __builtin_amdgcn_global_load_lds( \
    (const __attribute__((address_space(1))) void*)(g), \
    (__attribute__((address_space(3))) void*)(l), 16, 0, 0)

// ---------------------------------------------------------------------------
// pack: fused NCHW->NHWC bf16 transposes (x, z) + weight repacks (unchanged,
// verified round 7).
// ---------------------------------------------------------------------------
__global__ __launch_bounds__(256) void pack_kernel(
    const float* __restrict__ x, const float* __restrict__ z,
    const float* __restrict__ wxa, const float* __restrict__ wxb,
    const float* __restrict__ wza, const float* __restrict__ wzb,
    ushort_t* __restrict__ xh, ushort_t* __restrict__ zh,
    ushort_t* __restrict__ Bxo, ushort_t* __restrict__ Bzo)
{
  __shared__ ushort_t t[64 * 260];
  int id = blockIdx.x;
  int tid = threadIdx.x;
  if (id < 1024) {                       // x: [32,256,32,32] -> [b,h][w][c]
    int b = id >> 5, h = id & 31;
    const float* src = x + (size_t)b * 262144 + h * 32;
#pragma unroll
    for (int it = 0; it < 8; ++it) {     // 2048 quads
      int f = it * 256 + tid;
      int c = f >> 3, wq = f & 7;
      float4 v = *reinterpret_cast<const float4*>(src + c * 1024 + wq * 4);
      t[(4 * wq + 0) * 260 + c] = f2bf(v.x);
      t[(4 * wq + 1) * 260 + c] = f2bf(v.y);
      t[(4 * wq + 2) * 260 + c] = f2bf(v.z);
      t[(4 * wq + 3) * 260 + c] = f2bf(v.w);
    }
    __syncthreads();
    ushort_t* dst = xh + (size_t)(b * 32 + h) * 8192;
#pragma unroll
    for (int it = 0; it < 8; ++it) {
      int Q = it * 256 + tid;
      int w = Q >> 6, c0 = (Q & 63) * 4;
      u16x4 pk = *reinterpret_cast<const u16x4*>(&t[w * 260 + c0]);
      *reinterpret_cast<u16x4*>(&dst[w * 256 + c0]) = pk;
    }
  } else if (id < 1056) {                // z: [32,256,8,8] -> [b][hw][c]
    int b = id - 1024;
    const float* src = z + (size_t)b * 16384;
#pragma unroll
    for (int it = 0; it < 16; ++it) {    // 4096 quads
      int f = it * 256 + tid;
      int c = f >> 4, hq = f & 15;
      float4 v = *reinterpret_cast<const float4*>(src + c * 64 + hq * 4);
      t[(4 * hq + 0) * 260 + c] = f2bf(v.x);
      t[(4 * hq + 1) * 260 + c] = f2bf(v.y);
      t[(4 * hq + 2) * 260 + c] = f2bf(v.z);
      t[(4 * hq + 3) * 260 + c] = f2bf(v.w);
    }
    __syncthreads();
    ushort_t* dst = zh + (size_t)b * 16384;
#pragma unroll
    for (int it = 0; it < 16; ++it) {
      int Q = it * 256 + tid;
      int hw = Q >> 6, c0 = (Q & 63) * 4;
      u16x4 pk = *reinterpret_cast<const u16x4*>(&t[hw * 260 + c0]);
      *reinterpret_cast<u16x4*>(&dst[hw * 256 + c0]) = pk;
    }
  } else {                               // weights -> [n][k], k = tap*256+ci
    float* tf = reinterpret_cast<float*>(t);
    int wid = id - 1056;
    int isZ = wid >> 9;
    int n   = wid & 511;
    const float* s0 = isZ ? wza : wxa;
    const float* s1 = isZ ? wzb : wxb;
    const float* src = (n < 256 ? s0 : s1) + (size_t)(n & 255) * 2304;
#pragma unroll
    for (int it = 0; it < 3; ++it) {
      int f = it * 256 + tid;
      if (f < 576) {
        float4 v = *reinterpret_cast<const float4*>(src + f * 4);
        *reinterpret_cast<float4*>(&tf[f * 4]) = v;
      }
    }
    __syncthreads();
    ushort_t* dst = (isZ ? Bzo : Bxo) + (size_t)n * 2304;
#pragma unroll
    for (int it = 0; it < 9; ++it) {
      int k = it * 256 + tid;
      int tap = k >> 8, ci = k & 255;
      dst[k] = f2bf(tf[ci * 9 + tap]);
    }
  }
}

// ---------------------------------------------------------------------------
// implicit-GEMM conv + BN epilogue.
// Double-buffered LDS, ONE barrier per K-step: stage(next) issued BEFORE
// compute(current); __syncthreads' implicit vmcnt(0) drains the prefetch
// after it had the whole compute phase in flight. Race analysis: barrier at
// end of iter k guarantees (a) this iter's stage writes to buf[k+1&1] landed
// (per-wave vmcnt0 before barrier), (b) all waves finished reading buf[k&1]
// before iter k+1 overwrites it. XOR chunk swizzle unchanged (verified 0
// conflicts, rule #21 both-sides).
// tile 128x128, BK=64, 4 waves (2x2), mfma 16x16x32 bf16.
// ---------------------------------------------------------------------------
template<int OW, int OWH, int IW, int IMG, typename OutT>
__device__ __forceinline__ void conv_body(
    int mtile, int ntile,
    const ushort_t* __restrict__ Aimg, const ushort_t* __restrict__ Bw,
    const float* __restrict__ g0, const float* __restrict__ b0,
    const float* __restrict__ m0, const float* __restrict__ v0,
    const float* __restrict__ g1, const float* __restrict__ b1,
    const float* __restrict__ m1, const float* __restrict__ v1,
    OutT* __restrict__ out0, OutT* __restrict__ out1,
    ushort_t* lds)                       // [2 dbuf][A 8192 | B 8192]
{
  const int tid  = threadIdx.x;
  const int lane = tid & 63;
  const int wave = tid >> 6;
  const int wr   = wave >> 1, wc = wave & 1;

  const int chunk = (tid & 7) ^ ((tid >> 3) & 7);
  int abase[4], bbase[4];
#pragma unroll
  for (int i = 0; i < 4; ++i) {
    int row = i * 32 + (tid >> 3);
    int m_g = mtile * 128 + row;
    int b   = m_g / OWH;
    int s   = m_g - b * OWH;
    int oh  = s / OW;
    int ow  = s - oh * OW;
    abase[i] = (b * IMG + oh * IW + ow) * 256 + chunk * 8;
    int n_g = ntile * 128 + row;
    bbase[i] = n_g * 2304 + chunk * 8;
  }

  auto stage = [&](int buf, int ks) {
    const int k0  = ks * 64;
    const int tap = k0 >> 8;
    const int ci0 = k0 & 255;
    const int kh  = tap / 3;
    const int kw  = tap - kh * 3;
    const int aoff = (kh * IW + kw) * 256 + ci0;
    ushort_t* dstA = lds + buf * 16384;
    ushort_t* dstB = dstA + 8192;
#pragma unroll
    for (int i = 0; i < 4; ++i) {
      GLDS16(Aimg + abase[i] + aoff, &dstA[(i * 256 + tid) * 8]);
      GLDS16(Bw + bbase[i] + k0,     &dstB[(i * 256 + tid) * 8]);
    }
  };

  f32x4 acc[4][4];
#pragma unroll
  for (int i = 0; i < 4; ++i)
#pragma unroll
    for (int j = 0; j < 4; ++j)
      acc[i][j] = (f32x4){0.f, 0.f, 0.f, 0.f};

  const int lrow = lane & 15;
  const int lk   = lane >> 4;
  const int rA   = wr * 64;
  const int rB   = wc * 64;
  const int sw   = lrow & 7;

  stage(0, 0);
  __syncthreads();

  for (int ks = 0; ks < 36; ++ks) {
    const int cur = ks & 1;
    if (ks < 35) stage(cur ^ 1, ks + 1);          // prefetch next tile
    const ushort_t* As = lds + cur * 16384;
    const ushort_t* Bs = As + 8192;
#pragma unroll
    for (int kc = 0; kc < 2; ++kc) {
      bf16x8 af[4], bfr[4];
#pragma unroll
      for (int mi = 0; mi < 4; ++mi)
        af[mi] = *(const bf16x8*)&As[(rA + mi * 16 + lrow) * 64 + (((kc << 2) | lk) ^ sw) * 8];
#pragma unroll
      for (int ni = 0; ni < 4; ++ni)
        bfr[ni] = *(const bf16x8*)&Bs[(rB + ni * 16 + lrow) * 64 + (((kc << 2) | lk) ^ sw) * 8];
#pragma unroll
      for (int mi = 0; mi < 4; ++mi)
#pragma unroll
        for (int ni = 0; ni < 4; ++ni)
          acc[mi][ni] = __builtin_amdgcn_mfma_f32_16x16x32_bf16(
              af[mi], bfr[ni], acc[mi][ni], 0, 0, 0);
    }
    __syncthreads();                              // drains prefetch + readers
  }

#pragma unroll
  for (int ni = 0; ni < 4; ++ni) {
    int n_g  = ntile * 128 + rB + ni * 16 + lrow;
    int path = n_g >> 8;
    int co   = n_g & 255;
    const float* G  = path ? g1 : g0;
    const float* Bb = path ? b1 : b0;
    const float* Mm = path ? m1 : m0;
    const float* Vv = path ? v1 : v0;
    float iv = G[co] * rsqrtf(Vv[co] + EPS);
    float be = Bb[co] - Mm[co] * iv;
    OutT* outp = path ? out1 : out0;
#pragma unroll
    for (int mi = 0; mi < 4; ++mi) {
      int m_g = mtile * 128 + rA + mi * 16 + lk * 4;
      int b   = m_g / OWH;
      int s   = m_g - b * OWH;
      if constexpr (sizeof(OutT) == 2) {
        u16x4 pk;
#pragma unroll
        for (int r = 0; r < 4; ++r) pk[r] = f2bf(acc[mi][ni][r] * iv + be);
        *reinterpret_cast<u16x4*>(&outp[(size_t)(b * 256 + co) * OWH + s]) = pk;
      } else {
        f32x4 pk;
#pragma unroll
        for (int r = 0; r < 4; ++r) pk[r] = acc[mi][ni][r] * iv + be;
        *reinterpret_cast<f32x4*>(&outp[(size_t)(b * 256 + co) * OWH + s]) = pk;
      }
    }
  }
}

__global__ __launch_bounds__(256) void conv_fused_kernel(
    const ushort_t* __restrict__ xh, const ushort_t* __restrict__ zh,
    const ushort_t* __restrict__ Bx, const ushort_t* __restrict__ Bz,
    const float* Gcx, const float* Bcx, const float* Mcx, const float* Vcx,
    const float* Grx, const float* Brx, const float* Mrx, const float* Vrx,
    const float* Gcz, const float* Bcz, const float* Mcz, const float* Vcz,
    const float* Grz, const float* Brz, const float* Mrz, const float* Vrz,
    ushort_t* __restrict__ cls_xf, ushort_t* __restrict__ reg_xf,
    float* __restrict__ cls_zf, float* __restrict__ reg_zf)
{
  __shared__ ushort_t lds[2 * 16384];   // 64 KB double buffer
  int bid = blockIdx.x;
  if (bid < 900) {
    // bijective XCD-chunk swizzle (m204): 900 = 4*113 + 4*112
    int xcd = bid & 7, within = bid >> 3;
    int id = (xcd < 4 ? xcd * 113 : 452 + (xcd - 4) * 112) + within;
    conv_body<30, 900, 32, 1024, ushort_t>(id >> 2, id & 3, xh, Bx,
        Gcx, Bcx, Mcx, Vcx, Grx, Brx, Mrx, Vrx, cls_xf, reg_xf, lds);
  } else {
    int j = bid - 900;
    conv_body<6, 36, 8, 64, float>(j >> 2, j & 3, zh, Bz,
        Gcz, Bcz, Mcz, Vcz, Grz, Brz, Mrz, Vrz, cls_zf, reg_zf, lds);
  }
}

// ---------------------------------------------------------------------------
// fused depthwise xcorr, strip version: each thread computes a 1x5 output
// strip (5 independent acc chains; 60 LDS reads per 180 FMA vs 1:1 before).
// Block = 2 (b,c) pairs (128 threads each). grid 8192: path = bid>>12.
// ---------------------------------------------------------------------------
__global__ __launch_bounds__(256) void xcorr_kernel(
    const float* __restrict__ cls_zf, const float* __restrict__ reg_zf,
    const ushort_t* __restrict__ cls_xf, const ushort_t* __restrict__ reg_xf,
    float* __restrict__ out)
{
  int bid   = blockIdx.x;
  int path  = bid >> 12;
  int pair0 = (bid & 4095) * 2;
  int tid   = threadIdx.x;
  int half  = tid >> 7;                  // which pair
  int t     = tid & 127;
  int bc    = pair0 + half;
  __shared__ float sx[2][912];
  const float*    zp = (path ? reg_zf : cls_zf) + (size_t)bc * 36;
  const ushort_t* xp = (path ? reg_xf : cls_xf) + (size_t)bc * 900;
  {                                      // 225 quads per pair, 128 threads
    u16x4 v = *reinterpret_cast<const u16x4*>(xp + t * 4);
    sx[half][t * 4 + 0] = bf2f(v[0]);
    sx[half][t * 4 + 1] = bf2f(v[1]);
    sx[half][t * 4 + 2] = bf2f(v[2]);
    sx[half][t * 4 + 3] = bf2f(v[3]);
    if (t < 97) {
      u16x4 w = *reinterpret_cast<const u16x4*>(xp + (t + 128) * 4);
      sx[half][(t + 128) * 4 + 0] = bf2f(w[0]);
      sx[half][(t + 128) * 4 + 1] = bf2f(w[1]);
      sx[half][(t + 128) * 4 + 2] = bf2f(w[2]);
      sx[half][(t + 128) * 4 + 3] = bf2f(w[3]);
    }
  }
  float zreg[36];
#pragma unroll
  for (int i = 0; i < 36; ++i) zreg[i] = zp[i];   // broadcast, L2-hot
  __syncthreads();
  if (t < 125) {
    int p = t / 5, q0 = (t % 5) * 5;
    float a0 = 0.f, a1 = 0.f, a2 = 0.f, a3 = 0.f, a4 = 0.f;
#pragma unroll
    for (int u = 0; u < 6; ++u) {
      const float* row = &sx[half][(p + u) * 30 + q0];
      float xw[10];
#pragma unroll
      for (int w = 0; w < 10; ++w) xw[w] = row[w];
#pragma unroll
      for (int v = 0; v < 6; ++v) {
        float zv = zreg[u * 6 + v];
        a0 += zv * xw[v];
        a1 += zv * xw[v + 1];
        a2 += zv * xw[v + 2];
        a3 += zv * xw[v + 3];
        a4 += zv * xw[v + 4];
      }
    }
    float* op = out + (size_t)path * 5120000 + (size_t)bc * 625 + p * 25 + q0;
    op[0] = a0; op[1] = a1; op[2] = a2; op[3] = a3; op[4] = a4;
  }
}

// ---------------------------------------------------------------------------
extern "C" void kernel_launch(void* const* d_in, const int* in_sizes, int n_in,
                              void* d_out, int out_size, void* d_ws, size_t ws_size,
                              hipStream_t stream) {
  const float* z = (const float*)d_in[0];
  const float* x = (const float*)d_in[1];
  const float *W[4], *G[4], *Bb[4], *M[4], *V[4];
  for (int p = 0; p < 4; ++p) {
    W[p]  = (const float*)d_in[2 + p * 5 + 0];
    G[p]  = (const float*)d_in[2 + p * 5 + 1];
    Bb[p] = (const float*)d_in[2 + p * 5 + 2];
    M[p]  = (const float*)d_in[2 + p * 5 + 3];
    V[p]  = (const float*)d_in[2 + p * 5 + 4];
  }

  char* ws = (char*)d_ws;
  ushort_t* xhwc   = (ushort_t*)ws; ws += (size_t)32*32*32*256 * 2;   // 16.78 MB
  ushort_t* zhwc   = (ushort_t*)ws; ws += (size_t)32*8*8*256 * 2;     //  1.05 MB
  ushort_t* Bx     = (ushort_t*)ws; ws += (size_t)512*2304 * 2;       //  2.36 MB
  ushort_t* Bz     = (ushort_t*)ws; ws += (size_t)512*2304 * 2;       //  2.36 MB
  ushort_t* cls_xf = (ushort_t*)ws; ws += (size_t)32*256*900 * 2;     // 14.75 MB
  ushort_t* reg_xf = (ushort_t*)ws; ws += (size_t)32*256*900 * 2;     // 14.75 MB
  float* cls_zf    = (float*)ws;    ws += (size_t)32*256*36 * 4;      //  1.18 MB
  float* reg_zf    = (float*)ws;    // + 1.18 MB -> 54.4 MB total

  float* outF = (float*)d_out;

  pack_kernel<<<2080, 256, 0, stream>>>(x, z, W[1], W[3], W[0], W[2],
                                        xhwc, zhwc, Bx, Bz);
  conv_fused_kernel<<<936, 256, 0, stream>>>(
      xhwc, zhwc, Bx, Bz,
      G[1], Bb[1], M[1], V[1], G[3], Bb[3], M[3], V[3],
      G[0], Bb[0], M[0], V[0], G[2], Bb[2], M[2], V[2],
      cls_xf, reg_xf, cls_zf, reg_zf);
  xcorr_kernel<<<8192, 256, 0, stream>>>(cls_zf, reg_zf, cls_xf, reg_xf, outF);
}

// Round 9
// 228.616 us; speedup vs baseline: 19.8110x; 1.0502x over previous
//
#include <hip/hip_runtime.h>

#define EPS 1e-5f

typedef __attribute__((ext_vector_type(8))) short bf16x8;
typedef __attribute__((ext_vector_type(4))) float f32x4;
typedef __attribute__((ext_vector_type(4))) unsigned short u16x4;
typedef unsigned short ushort_t;

__device__ __forceinline__ ushort_t f2bf(float f) {
  unsigned u = __float_as_uint(f);
  unsigned r = (u + 0x7fffu + ((u >> 16) & 1u)) >> 16;
  return (ushort_t)r;
}
__device__ __forceinline__ float bf2f(ushort_t h) {
  return __uint_as_float((unsigned)h << 16);
}

#define GLDS16(g, l) __builtin_amdgcn_global_load_lds( \
    (const __attribute__((address_space(1))) void*)(g), \
    (__attribute__((address_space(3))) void*)(l), 16, 0, 0)

// counted-vmcnt barrier (T4): wait own oldest loads, fence, raw barrier.
// rule #18: sched_barrier(0) around the asm so nothing crosses.
__device__ __forceinline__ void wait_bar6() {
  asm volatile("s_waitcnt vmcnt(6) lgkmcnt(0)" ::: "memory");
  __builtin_amdgcn_sched_barrier(0);
  __builtin_amdgcn_s_barrier();
  __builtin_amdgcn_sched_barrier(0);
}
__device__ __forceinline__ void wait_bar0() {
  asm volatile("s_waitcnt vmcnt(0) lgkmcnt(0)" ::: "memory");
  __builtin_amdgcn_sched_barrier(0);
  __builtin_amdgcn_s_barrier();
  __builtin_amdgcn_sched_barrier(0);
}

// ---------------------------------------------------------------------------
// pack: fused NCHW->NHWC bf16 transposes (x, z) + weight repacks (verified).
// ---------------------------------------------------------------------------
__global__ __launch_bounds__(256) void pack_kernel(
    const float* __restrict__ x, const float* __restrict__ z,
    const float* __restrict__ wxa, const float* __restrict__ wxb,
    const float* __restrict__ wza, const float* __restrict__ wzb,
    ushort_t* __restrict__ xh, ushort_t* __restrict__ zh,
    ushort_t* __restrict__ Bxo, ushort_t* __restrict__ Bzo)
{
  __shared__ ushort_t t[64 * 260];
  int id = blockIdx.x;
  int tid = threadIdx.x;
  if (id < 1024) {                       // x: [32,256,32,32] -> [b,h][w][c]
    int b = id >> 5, h = id & 31;
    const float* src = x + (size_t)b * 262144 + h * 32;
#pragma unroll
    for (int it = 0; it < 8; ++it) {     // 2048 quads
      int f = it * 256 + tid;
      int c = f >> 3, wq = f & 7;
      float4 v = *reinterpret_cast<const float4*>(src + c * 1024 + wq * 4);
      t[(4 * wq + 0) * 260 + c] = f2bf(v.x);
      t[(4 * wq + 1) * 260 + c] = f2bf(v.y);
      t[(4 * wq + 2) * 260 + c] = f2bf(v.z);
      t[(4 * wq + 3) * 260 + c] = f2bf(v.w);
    }
    __syncthreads();
    ushort_t* dst = xh + (size_t)(b * 32 + h) * 8192;
#pragma unroll
    for (int it = 0; it < 8; ++it) {
      int Q = it * 256 + tid;
      int w = Q >> 6, c0 = (Q & 63) * 4;
      u16x4 pk = *reinterpret_cast<const u16x4*>(&t[w * 260 + c0]);
      *reinterpret_cast<u16x4*>(&dst[w * 256 + c0]) = pk;
    }
  } else if (id < 1056) {                // z: [32,256,8,8] -> [b][hw][c]
    int b = id - 1024;
    const float* src = z + (size_t)b * 16384;
#pragma unroll
    for (int it = 0; it < 16; ++it) {    // 4096 quads
      int f = it * 256 + tid;
      int c = f >> 4, hq = f & 15;
      float4 v = *reinterpret_cast<const float4*>(src + c * 64 + hq * 4);
      t[(4 * hq + 0) * 260 + c] = f2bf(v.x);
      t[(4 * hq + 1) * 260 + c] = f2bf(v.y);
      t[(4 * hq + 2) * 260 + c] = f2bf(v.z);
      t[(4 * hq + 3) * 260 + c] = f2bf(v.w);
    }
    __syncthreads();
    ushort_t* dst = zh + (size_t)b * 16384;
#pragma unroll
    for (int it = 0; it < 16; ++it) {
      int Q = it * 256 + tid;
      int hw = Q >> 6, c0 = (Q & 63) * 4;
      u16x4 pk = *reinterpret_cast<const u16x4*>(&t[hw * 260 + c0]);
      *reinterpret_cast<u16x4*>(&dst[hw * 256 + c0]) = pk;
    }
  } else {                               // weights -> [n][k], k = tap*256+ci
    float* tf = reinterpret_cast<float*>(t);
    int wid = id - 1056;
    int isZ = wid >> 9;
    int n   = wid & 511;
    const float* s0 = isZ ? wza : wxa;
    const float* s1 = isZ ? wzb : wxb;
    const float* src = (n < 256 ? s0 : s1) + (size_t)(n & 255) * 2304;
#pragma unroll
    for (int it = 0; it < 3; ++it) {
      int f = it * 256 + tid;
      if (f < 576) {
        float4 v = *reinterpret_cast<const float4*>(src + f * 4);
        *reinterpret_cast<float4*>(&tf[f * 4]) = v;
      }
    }
    __syncthreads();
    ushort_t* dst = (isZ ? Bzo : Bxo) + (size_t)n * 2304;
#pragma unroll
    for (int it = 0; it < 9; ++it) {
      int k = it * 256 + tid;
      int tap = k >> 8, ci = k & 255;
      dst[k] = f2bf(tf[ci * 9 + tap]);
    }
  }
}

// ---------------------------------------------------------------------------
// implicit-GEMM conv + BN epilogue — 128M x 256N tile, 8 waves (2Mx4N),
// 3-buffer distance-2 prefetch, counted vmcnt(6) + raw s_barrier (T3+T4).
// Buffer b: tile kt lives in buf kt%3; stage(kt+2) issued at iter kt into a
// buffer last read at iter kt-1 (barrier-protected). End-of-iter vmcnt(6)
// retires the older in-flight tile (kt+1, 6 loads) while this iter's 6 stay
// in flight across the barrier. XOR chunk swizzle as verified (0 conflicts).
// ---------------------------------------------------------------------------
template<int OW, int OWH, int IW, int IMG, typename OutT>
__device__ __forceinline__ void conv_body(
    int mtile, int ntile,
    const ushort_t* __restrict__ Aimg, const ushort_t* __restrict__ Bw,
    const float* __restrict__ g0, const float* __restrict__ b0,
    const float* __restrict__ m0, const float* __restrict__ v0,
    const float* __restrict__ g1, const float* __restrict__ b1,
    const float* __restrict__ m1, const float* __restrict__ v1,
    OutT* __restrict__ out0, OutT* __restrict__ out1,
    ushort_t* lds)                       // 3 bufs x (A 8192 | B 16384) ushorts
{
  const int tid  = threadIdx.x;          // 0..511
  const int lane = tid & 63;
  const int wave = tid >> 6;             // 0..7
  const int wr   = wave >> 2, wc = wave & 3;

  const int chunk = (tid & 7) ^ ((tid >> 3) & 7);
  int abase[2], bbase[4];
#pragma unroll
  for (int i = 0; i < 2; ++i) {
    int row = i * 64 + (tid >> 3);       // 0..127
    int m_g = mtile * 128 + row;
    int b   = m_g / OWH;
    int s   = m_g - b * OWH;
    int oh  = s / OW;
    int ow  = s - oh * OW;
    abase[i] = (b * IMG + oh * IW + ow) * 256 + chunk * 8;
  }
#pragma unroll
  for (int i = 0; i < 4; ++i) {
    int row = i * 64 + (tid >> 3);       // 0..255
    int n_g = ntile * 256 + row;
    bbase[i] = n_g * 2304 + chunk * 8;
  }

  auto stage = [&](int buf, int kt) {
    const int k0  = kt * 64;
    const int tap = k0 >> 8;
    const int ci0 = k0 & 255;
    const int kh  = tap / 3;
    const int kw  = tap - kh * 3;
    const int aoff = (kh * IW + kw) * 256 + ci0;
    ushort_t* dstA = lds + buf * 24576;
    ushort_t* dstB = dstA + 8192;
#pragma unroll
    for (int i = 0; i < 2; ++i)
      GLDS16(Aimg + abase[i] + aoff, &dstA[(i * 512 + tid) * 8]);
#pragma unroll
    for (int i = 0; i < 4; ++i)
      GLDS16(Bw + bbase[i] + k0, &dstB[(i * 512 + tid) * 8]);
  };

  f32x4 acc[4][4];
#pragma unroll
  for (int i = 0; i < 4; ++i)
#pragma unroll
    for (int j = 0; j < 4; ++j)
      acc[i][j] = (f32x4){0.f, 0.f, 0.f, 0.f};

  const int lrow = lane & 15;
  const int lk   = lane >> 4;
  const int rA   = wr * 64;              // 0 / 64   (A rows, 128)
  const int rB   = wc * 64;              // 0..192   (B rows, 256)
  const int sw   = lrow & 7;

  auto compute = [&](int buf) {
    const ushort_t* As = lds + buf * 24576;
    const ushort_t* Bs = As + 8192;
#pragma unroll
    for (int kc = 0; kc < 2; ++kc) {
      bf16x8 af[4], bfr[4];
#pragma unroll
      for (int mi = 0; mi < 4; ++mi)
        af[mi] = *(const bf16x8*)&As[(rA + mi * 16 + lrow) * 64 + (((kc << 2) | lk) ^ sw) * 8];
#pragma unroll
      for (int ni = 0; ni < 4; ++ni)
        bfr[ni] = *(const bf16x8*)&Bs[(rB + ni * 16 + lrow) * 64 + (((kc << 2) | lk) ^ sw) * 8];
#pragma unroll
      for (int mi = 0; mi < 4; ++mi)
#pragma unroll
        for (int ni = 0; ni < 4; ++ni)
          acc[mi][ni] = __builtin_amdgcn_mfma_f32_16x16x32_bf16(
              af[mi], bfr[ni], acc[mi][ni], 0, 0, 0);
    }
  };

  // prologue: tiles 0,1 in flight; vmcnt(6) retires tile 0 (oldest 6 loads)
  stage(0, 0);
  stage(1, 1);
  wait_bar6();

  int cb = 0;
  for (int kt = 0; kt < 34; ++kt) {
    int sb = (cb == 0) ? 2 : cb - 1;     // (cb+2)%3
    stage(sb, kt + 2);
    compute(cb);
    wait_bar6();                          // tile kt+1 landed; kt+2 in flight
    cb = (cb == 2) ? 0 : cb + 1;
  }
  compute(cb);                            // kt=34 (buf 1)
  wait_bar0();                            // drain tile 35
  cb = (cb == 2) ? 0 : cb + 1;
  compute(cb);                            // kt=35 (buf 2)

  // epilogue: BN fold + packed scatter to NCHW
#pragma unroll
  for (int ni = 0; ni < 4; ++ni) {
    int n_g  = ntile * 256 + rB + ni * 16 + lrow;
    int path = n_g >> 8;
    int co   = n_g & 255;
    const float* G  = path ? g1 : g0;
    const float* Bb = path ? b1 : b0;
    const float* Mm = path ? m1 : m0;
    const float* Vv = path ? v1 : v0;
    float iv = G[co] * rsqrtf(Vv[co] + EPS);
    float be = Bb[co] - Mm[co] * iv;
    OutT* outp = path ? out1 : out0;
#pragma unroll
    for (int mi = 0; mi < 4; ++mi) {
      int m_g = mtile * 128 + rA + mi * 16 + lk * 4;
      int b   = m_g / OWH;
      int s   = m_g - b * OWH;
      if constexpr (sizeof(OutT) == 2) {
        u16x4 pk;
#pragma unroll
        for (int r = 0; r < 4; ++r) pk[r] = f2bf(acc[mi][ni][r] * iv + be);
        *reinterpret_cast<u16x4*>(&outp[(size_t)(b * 256 + co) * OWH + s]) = pk;
      } else {
        f32x4 pk;
#pragma unroll
        for (int r = 0; r < 4; ++r) pk[r] = acc[mi][ni][r] * iv + be;
        *reinterpret_cast<f32x4*>(&outp[(size_t)(b * 256 + co) * OWH + s]) = pk;
      }
    }
  }
}

__global__ __launch_bounds__(512, 1) void conv_fused_kernel(
    const ushort_t* __restrict__ xh, const ushort_t* __restrict__ zh,
    const ushort_t* __restrict__ Bx, const ushort_t* __restrict__ Bz,
    const float* Gcx, const float* Bcx, const float* Mcx, const float* Vcx,
    const float* Grx, const float* Brx, const float* Mrx, const float* Vrx,
    const float* Gcz, const float* Bcz, const float* Mcz, const float* Vcz,
    const float* Grz, const float* Brz, const float* Mrz, const float* Vrz,
    ushort_t* __restrict__ cls_xf, ushort_t* __restrict__ reg_xf,
    float* __restrict__ cls_zf, float* __restrict__ reg_zf)
{
  __shared__ ushort_t lds[3 * 24576];    // 144 KB: 3 bufs x (A 16KB + B 32KB)
  int orig = blockIdx.x;                 // 468 = 450 x-blocks + 18 z-blocks
  // bijective m204 XCD swizzle: q=58, r=4
  int xcd = orig & 7, local = orig >> 3;
  int id = (xcd < 4 ? xcd * 59 : 236 + (xcd - 4) * 58) + local;
  if (id < 450) {
    conv_body<30, 900, 32, 1024, ushort_t>(id >> 1, id & 1, xh, Bx,
        Gcx, Bcx, Mcx, Vcx, Grx, Brx, Mrx, Vrx, cls_xf, reg_xf, lds);
  } else {
    int j = id - 450;
    conv_body<6, 36, 8, 64, float>(j >> 1, j & 1, zh, Bz,
        Gcz, Bcz, Mcz, Vcz, Grz, Brz, Mrz, Vrz, cls_zf, reg_zf, lds);
  }
}

// ---------------------------------------------------------------------------
// fused depthwise xcorr (verified round 8): 1x5 strip per thread, 2 pairs
// per block, z in registers.
// ---------------------------------------------------------------------------
__global__ __launch_bounds__(256) void xcorr_kernel(
    const float* __restrict__ cls_zf, const float* __restrict__ reg_zf,
    const ushort_t* __restrict__ cls_xf, const ushort_t* __restrict__ reg_xf,
    float* __restrict__ out)
{
  int bid   = blockIdx.x;
  int path  = bid >> 12;
  int pair0 = (bid & 4095) * 2;
  int tid   = threadIdx.x;
  int half  = tid >> 7;
  int t     = tid & 127;
  int bc    = pair0 + half;
  __shared__ float sx[2][912];
  const float*    zp = (path ? reg_zf : cls_zf) + (size_t)bc * 36;
  const ushort_t* xp = (path ? reg_xf : cls_xf) + (size_t)bc * 900;
  {
    u16x4 v = *reinterpret_cast<const u16x4*>(xp + t * 4);
    sx[half][t * 4 + 0] = bf2f(v[0]);
    sx[half][t * 4 + 1] = bf2f(v[1]);
    sx[half][t * 4 + 2] = bf2f(v[2]);
    sx[half][t * 4 + 3] = bf2f(v[3]);
    if (t < 97) {
      u16x4 w = *reinterpret_cast<const u16x4*>(xp + (t + 128) * 4);
      sx[half][(t + 128) * 4 + 0] = bf2f(w[0]);
      sx[half][(t + 128) * 4 + 1] = bf2f(w[1]);
      sx[half][(t + 128) * 4 + 2] = bf2f(w[2]);
      sx[half][(t + 128) * 4 + 3] = bf2f(w[3]);
    }
  }
  float zreg[36];
#pragma unroll
  for (int i = 0; i < 36; ++i) zreg[i] = zp[i];
  __syncthreads();
  if (t < 125) {
    int p = t / 5, q0 = (t % 5) * 5;
    float a0 = 0.f, a1 = 0.f, a2 = 0.f, a3 = 0.f, a4 = 0.f;
#pragma unroll
    for (int u = 0; u < 6; ++u) {
      const float* row = &sx[half][(p + u) * 30 + q0];
      float xw[10];
#pragma unroll
      for (int w = 0; w < 10; ++w) xw[w] = row[w];
#pragma unroll
      for (int v = 0; v < 6; ++v) {
        float zv = zreg[u * 6 + v];
        a0 += zv * xw[v];
        a1 += zv * xw[v + 1];
        a2 += zv * xw[v + 2];
        a3 += zv * xw[v + 3];
        a4 += zv * xw[v + 4];
      }
    }
    float* op = out + (size_t)path * 5120000 + (size_t)bc * 625 + p * 25 + q0;
    op[0] = a0; op[1] = a1; op[2] = a2; op[3] = a3; op[4] = a4;
  }
}

// ---------------------------------------------------------------------------
extern "C" void kernel_launch(void* const* d_in, const int* in_sizes, int n_in,
                              void* d_out, int out_size, void* d_ws, size_t ws_size,
                              hipStream_t stream) {
  const float* z = (const float*)d_in[0];
  const float* x = (const float*)d_in[1];
  const float *W[4], *G[4], *Bb[4], *M[4], *V[4];
  for (int p = 0; p < 4; ++p) {
    W[p]  = (const float*)d_in[2 + p * 5 + 0];
    G[p]  = (const float*)d_in[2 + p * 5 + 1];
    Bb[p] = (const float*)d_in[2 + p * 5 + 2];
    M[p]  = (const float*)d_in[2 + p * 5 + 3];
    V[p]  = (const float*)d_in[2 + p * 5 + 4];
  }

  char* ws = (char*)d_ws;
  ushort_t* xhwc   = (ushort_t*)ws; ws += (size_t)32*32*32*256 * 2;   // 16.78 MB
  ushort_t* zhwc   = (ushort_t*)ws; ws += (size_t)32*8*8*256 * 2;     //  1.05 MB
  ushort_t* Bx     = (ushort_t*)ws; ws += (size_t)512*2304 * 2;       //  2.36 MB
  ushort_t* Bz     = (ushort_t*)ws; ws += (size_t)512*2304 * 2;       //  2.36 MB
  ushort_t* cls_xf = (ushort_t*)ws; ws += (size_t)32*256*900 * 2;     // 14.75 MB
  ushort_t* reg_xf = (ushort_t*)ws; ws += (size_t)32*256*900 * 2;     // 14.75 MB
  float* cls_zf    = (float*)ws;    ws += (size_t)32*256*36 * 4;      //  1.18 MB
  float* reg_zf    = (float*)ws;    // + 1.18 MB -> 54.4 MB total

  float* outF = (float*)d_out;

  pack_kernel<<<2080, 256, 0, stream>>>(x, z, W[1], W[3], W[0], W[2],
                                        xhwc, zhwc, Bx, Bz);
  conv_fused_kernel<<<468, 512, 0, stream>>>(
      xhwc, zhwc, Bx, Bz,
      G[1], Bb[1], M[1], V[1], G[3], Bb[3], M[3], V[3],
      G[0], Bb[0], M[0], V[0], G[2], Bb[2], M[2], V[2],
      cls_xf, reg_xf, cls_zf, reg_zf);
  xcorr_kernel<<<8192, 256, 0, stream>>>(cls_zf, reg_zf, cls_xf, reg_xf, outF);
}